// Round 3
// baseline (356.584 us; speedup 1.0000x reference)
//
#include <hip/hip_runtime.h>
#include <hip/hip_bf16.h>

#define NVOC 65
#define NE   32
#define HD   16
#define NB   65536
#define NROWS (NB * 8)                   // 524288
#define NLOG  (NROWS * NVOC)             // 34078720

// ---- LDS layout (float offsets into S[14618], 58472 B) ----
// Phase 1-2 staging (dead after phase 2, overlaid by A):
//   tok@0(2080) pos@2080(256) Wq@2336(512) Wk@2848(512) Wv@3360(512)
// A (tables, live phase 3+): G1@0(4225) TVL@4225(4225) G2@8450(520)
//   G3@8970(520) G4@9490(64) PVL@9554(520)         -> A ends 10074
// B (projections, live phases 2-3, dead in 4):
//   TQ@10074(1040) TK@11114(1040) TV@12154(1040)
//   PQ@13194(128)  PK@13322(128)  PV@13450(128)    -> ends 13578
// Wlm staging @13578(1040)                          -> ends 14618
// Phase 4 overlays B: Es@10074 ([4][8][72]), red@12378(256)

static __device__ __forceinline__ float b2f(__hip_bfloat16 x) { return __bfloat162float(x); }
static __device__ __forceinline__ float readlane_f(float v, int l) {
  return __uint_as_float(__builtin_amdgcn_readlane(__float_as_uint(v), l));
}

// pre: zero loss accumulator; detect input dtype from tok_emb bit patterns.
// bf16-truth: first 128 halves are all bf16 of N(0,0.02) -> |x| <= 4 always.
// fp32-truth: even halves are fp32 mantissa garbage -> random exponents, fails w.h.p.
__global__ void bigram_pre(const unsigned short* __restrict__ toku,
                           float* __restrict__ wsf, int* __restrict__ wsi) {
  if (threadIdx.x == 0) {
    wsf[0] = 0.f;
    int ok = 1;
    for (int i = 0; i < 128; ++i) {
      float f = __uint_as_float((unsigned int)toku[i] << 16);
      float a = fabsf(f);
      if (!(a <= 4.0f)) ok = 0;   // NaN/inf/huge -> not bf16
    }
    wsi[1] = ok;                  // 1 = bf16 inputs/outputs, 0 = fp32
  }
}

template <bool BF16>
static __device__ __forceinline__ float ldf(const void* p, int i) {
  if (BF16) return b2f(((const __hip_bfloat16*)p)[i]);
  return ((const float*)p)[i];
}

template <bool BF16>
__global__ __launch_bounds__(256) void bigram_main(
    const int* __restrict__ idx, const int* __restrict__ tgt,
    const void* __restrict__ tok, const void* __restrict__ pos,
    const void* __restrict__ Wk, const void* __restrict__ bk,
    const void* __restrict__ Wq, const void* __restrict__ bq,
    const void* __restrict__ Wv, const void* __restrict__ bv,
    const void* __restrict__ Wlm, const void* __restrict__ blm,
    float* __restrict__ wsf, const int* __restrict__ wsi, void* __restrict__ outv)
{
  if (wsi[1] != (BF16 ? 1 : 0)) return;   // wrong-dtype instantiation: null dispatch
  __shared__ float S[14618];
  const int tid = threadIdx.x;

  // ---- phase 1: stage inputs -> f32 in LDS ----
  for (int o = tid; o < 2080; o += 256) S[o] = ldf<BF16>(tok, o);
  for (int o = tid; o < 256;  o += 256) S[2080 + o] = ldf<BF16>(pos, o);
  for (int o = tid; o < 512;  o += 256) {
    S[2336 + o] = ldf<BF16>(Wq, o); S[2848 + o] = ldf<BF16>(Wk, o); S[3360 + o] = ldf<BF16>(Wv, o);
  }
  for (int o = tid; o < 1040; o += 256) S[13578 + o] = ldf<BF16>(Wlm, o);
  __syncthreads();

  // ---- phase 2: TQ/TK/TV (65x16) and PQ/PK/PV (8x16, biases folded) ----
  for (int o = tid; o < 1168; o += 256) {
    if (o < 1040) {
      const int a = o >> 4, h = o & 15;
      float sq = 0.f, sk = 0.f, sv = 0.f;
      #pragma unroll
      for (int c = 0; c < NE; ++c) {
        const float e = S[a*32 + c];
        sq = fmaf(e, S[2336 + c*16 + h], sq);
        sk = fmaf(e, S[2848 + c*16 + h], sk);
        sv = fmaf(e, S[3360 + c*16 + h], sv);
      }
      S[10074 + o] = sq; S[11114 + o] = sk; S[12154 + o] = sv;
    } else {
      const int o2 = o - 1040, t = o2 >> 4, h = o2 & 15;
      float sq = ldf<BF16>(bq, h), sk = ldf<BF16>(bk, h), sv = ldf<BF16>(bv, h);
      #pragma unroll
      for (int c = 0; c < NE; ++c) {
        const float e = S[2080 + t*32 + c];
        sq = fmaf(e, S[2336 + c*16 + h], sq);
        sk = fmaf(e, S[2848 + c*16 + h], sk);
        sv = fmaf(e, S[3360 + c*16 + h], sv);
      }
      S[13194 + o2] = sq; S[13322 + o2] = sk; S[13450 + o2] = sv;
    }
  }
  __syncthreads();

  // ---- phase 3: tables. Writes A region, reads B + Wlm only ----
  for (int o = tid; o < 10074; o += 256) {
    float r = 0.f; int dst;
    if (o < 4225) {                       // G1[a][b] = 0.25 * TQ[a].TK[b]
      const int a = o / 65, b = o % 65;
      #pragma unroll
      for (int h = 0; h < HD; ++h) r = fmaf(S[10074 + a*16 + h], S[11114 + b*16 + h], r);
      r *= 0.25f; dst = o;
    } else if (o < 4745) {                // G2[a][s]
      const int o2 = o - 4225, a = o2 >> 3, s2 = o2 & 7;
      #pragma unroll
      for (int h = 0; h < HD; ++h) r = fmaf(S[10074 + a*16 + h], S[13322 + s2*16 + h], r);
      r *= 0.25f; dst = 8450 + o2;
    } else if (o < 5265) {                // G3[t][b]
      const int o2 = o - 4745, t2 = o2 / 65, b = o2 % 65;
      #pragma unroll
      for (int h = 0; h < HD; ++h) r = fmaf(S[13194 + t2*16 + h], S[11114 + b*16 + h], r);
      r *= 0.25f; dst = 8970 + o2;
    } else if (o < 5329) {                // G4[t][s]
      const int o2 = o - 5265, t2 = o2 >> 3, s2 = o2 & 7;
      #pragma unroll
      for (int h = 0; h < HD; ++h) r = fmaf(S[13194 + t2*16 + h], S[13322 + s2*16 + h], r);
      r *= 0.25f; dst = 9490 + o2;
    } else if (o < 9554) {                // TVL[a][j]
      const int o2 = o - 5329, a = o2 / 65, j = o2 % 65;
      #pragma unroll
      for (int h = 0; h < HD; ++h) r = fmaf(S[12154 + a*16 + h], S[13578 + h*65 + j], r);
      dst = 4225 + o2;
    } else {                              // PVL[s][j]
      const int o2 = o - 9554, s2 = o2 / 65, j = o2 % 65;
      #pragma unroll
      for (int h = 0; h < HD; ++h) r = fmaf(S[13450 + s2*16 + h], S[13578 + h*65 + j], r);
      dst = o;
    }
    S[dst] = r;
  }
  __syncthreads();

  // ---- phase 4: main loop (1 wave per batch iteration) ----
  const int lane = tid & 63;
  const int w    = tid >> 6;
  const int t    = lane >> 3;
  const int s    = lane & 7;
  const float g4 = S[9490 + lane];
  float pvl[8], pvl64[8];
  #pragma unroll
  for (int k = 0; k < 8; ++k) {
    pvl[k]   = S[9554 + k*65 + lane];
    pvl64[k] = S[9554 + k*65 + 64];
  }
  const float blmj  = ldf<BF16>(blm, lane);
  const float blm64 = ldf<BF16>(blm, 64);
  float* Es  = S + 10074;
  float* red = S + 12378;
  __hip_bfloat16* outb = (__hip_bfloat16*)outv;
  float*          outf = (float*)outv;

  const int gw = blockIdx.x * 4 + w;
  float acc_lsm = 0.f, acc_tl = 0.f;
  for (int itb = 0; itb < 8; ++itb) {
    const int b  = gw * 8 + itb;
    const int av = idx[b*8 + s];
    const int tv = tgt[b*8 + s];
    const int a_t = __shfl(av, t);
    float wr = S[a_t*65 + av] + S[8450 + a_t*8 + s] + S[8970 + t*65 + av] + g4;
    float e = (t >= s) ? __expf(wr) : 0.f;       // causal mask; softmax over t per column s
    float sm = e;
    sm += __shfl_xor(sm, 8); sm += __shfl_xor(sm, 16); sm += __shfl_xor(sm, 32);
    const float wsm = __fdividef(e, sm);
    float Ms[8], Ms64[8];
    #pragma unroll
    for (int k = 0; k < 8; ++k) {
      const int ak = __builtin_amdgcn_readlane(av, k);
      Ms[k]   = S[4225 + ak*65 + lane] + pvl[k];
      Ms64[k] = S[4225 + ak*65 + 64]  + pvl64[k];
    }
    const int rowbase = b * 520;
    #pragma unroll
    for (int tt = 0; tt < 8; ++tt) {
      float lg = blmj, lg64 = blm64;
      #pragma unroll
      for (int k = 0; k < 8; ++k) {
        const float wk = readlane_f(wsm, tt*8 + k);
        lg   = fmaf(wk, Ms[k],   lg);
        lg64 = fmaf(wk, Ms64[k], lg64);
      }
      if (BF16) {
        outb[rowbase + tt*65 + lane] = __float2bfloat16(lg);
        if (lane == 63) outb[rowbase + tt*65 + 64] = __float2bfloat16(lg64);
      } else {
        outf[rowbase + tt*65 + lane] = lg;
        if (lane == 63) outf[rowbase + tt*65 + 64] = lg64;
      }
      float ee = __expf(lg);
      if (lane == 63) ee += __expf(lg64);
      Es[(w*8 + tt)*72 + lane] = ee;
      const int tg  = __builtin_amdgcn_readlane(tv, tt);
      const int tgc = tg < 64 ? tg : 0;
      const float l_at_tg = readlane_f(lg, tgc);
      acc_tl += (tg < 64) ? l_at_tg : lg64;
    }
    const int t2 = lane & 7, jg = lane >> 3;
    float se = 0.f;
    #pragma unroll
    for (int i2 = 0; i2 < 8; ++i2) se += Es[(w*8 + t2)*72 + jg + 8*i2];
    se += __shfl_xor(se, 8); se += __shfl_xor(se, 16); se += __shfl_xor(se, 32);
    acc_lsm += __logf(se);
  }
  red[tid] = acc_lsm * 0.125f - acc_tl * 0.015625f;
  __syncthreads();
  if (tid < 64) {
    float v = red[tid] + red[tid+64] + red[tid+128] + red[tid+192];
    v += __shfl_xor(v, 1); v += __shfl_xor(v, 2);  v += __shfl_xor(v, 4);
    v += __shfl_xor(v, 8); v += __shfl_xor(v, 16); v += __shfl_xor(v, 32);
    if (tid == 0) atomicAdd(wsf, v);
  }
}

__global__ void bigram_fin(const float* __restrict__ wsf, const int* __restrict__ wsi,
                           void* __restrict__ outv) {
  if (threadIdx.x == 0) {
    const float L = wsf[0] * (1.0f / (float)NROWS);
    if (wsi[1]) ((__hip_bfloat16*)outv)[NLOG] = __float2bfloat16(L);
    else        ((float*)outv)[NLOG] = L;
  }
}

extern "C" void kernel_launch(void* const* d_in, const int* in_sizes, int n_in,
                              void* d_out, int out_size, void* d_ws, size_t ws_size,
                              hipStream_t stream) {
  const int* idx = (const int*)d_in[0];
  const int* tgt = (const int*)d_in[1];
  float* wsf = (float*)d_ws;
  int*   wsi = (int*)d_ws;

  bigram_pre<<<1, 64, 0, stream>>>((const unsigned short*)d_in[2], wsf, wsi);
  bigram_main<true><<<2048, 256, 0, stream>>>(idx, tgt, d_in[2], d_in[3], d_in[4], d_in[5],
                                              d_in[6], d_in[7], d_in[8], d_in[9], d_in[10],
                                              d_in[11], wsf, wsi, d_out);
  bigram_main<false><<<2048, 256, 0, stream>>>(idx, tgt, d_in[2], d_in[3], d_in[4], d_in[5],
                                               d_in[6], d_in[7], d_in[8], d_in[9], d_in[10],
                                               d_in[11], wsf, wsi, d_out);
  bigram_fin<<<1, 1, 0, stream>>>(wsf, wsi, d_out);
}

// Round 4
// 209.519 us; speedup vs baseline: 1.7019x; 1.7019x over previous
//
#include <hip/hip_runtime.h>
#include <hip/hip_bf16.h>

#define NVOC 65
#define NE   32
#define HD   16
#define NB   65536
#define NROWS (NB * 8)                   // 524288
#define NLOG  (NROWS * NVOC)             // 34078720

// ws layout (floats): ws[0]=loss acc; wsTab = ws+16 (64B aligned), 10074 floats:
//   G1@0(4225) TVL@4225(4225) G2@8450(520) G3@8970(520) G4@9490(64) PVL@9554(520)

static __device__ __forceinline__ float readlane_f(float v, int l) {
  return __uint_as_float(__builtin_amdgcn_readlane(__float_as_uint(v), l));
}

// ---- tables kernel: ONE block of 1024 threads; builds all lookup tables into ws ----
__global__ __launch_bounds__(1024) void bigram_tables(
    const float* __restrict__ tok, const float* __restrict__ pos,
    const float* __restrict__ Wk, const float* __restrict__ bk,
    const float* __restrict__ Wq, const float* __restrict__ bq,
    const float* __restrict__ Wv, const float* __restrict__ bv,
    const float* __restrict__ Wlm, float* __restrict__ ws)
{
  // LDS: tok@0(2080) pos@2080(256) Wq@2336(512) Wk@2848(512) Wv@3360(512)
  //      Wlm@3872(1040) TQ@4912(1040) TK@5952(1040) TV@6992(1040)
  //      PQ@8032(128) PK@8160(128) PV@8288(128)  -> 8416 floats
  __shared__ float S[8416];
  const int tid = threadIdx.x;
  if (tid == 0) ws[0] = 0.f;                       // loss accumulator
  for (int o = tid; o < 2080; o += 1024) S[o] = tok[o];
  for (int o = tid; o < 256;  o += 1024) S[2080 + o] = pos[o];
  for (int o = tid; o < 512;  o += 1024) {
    S[2336 + o] = Wq[o]; S[2848 + o] = Wk[o]; S[3360 + o] = Wv[o];
  }
  for (int o = tid; o < 1040; o += 1024) S[3872 + o] = Wlm[o];
  __syncthreads();

  for (int o = tid; o < 1168; o += 1024) {
    if (o < 1040) {
      const int a = o >> 4, h = o & 15;
      float sq = 0.f, sk = 0.f, sv = 0.f;
      #pragma unroll
      for (int c = 0; c < NE; ++c) {
        const float e = S[a*32 + c];
        sq = fmaf(e, S[2336 + c*16 + h], sq);
        sk = fmaf(e, S[2848 + c*16 + h], sk);
        sv = fmaf(e, S[3360 + c*16 + h], sv);
      }
      S[4912 + o] = sq; S[5952 + o] = sk; S[6992 + o] = sv;
    } else {
      const int o2 = o - 1040, t = o2 >> 4, h = o2 & 15;
      float sq = bq[h], sk = bk[h], sv = bv[h];
      #pragma unroll
      for (int c = 0; c < NE; ++c) {
        const float e = S[2080 + t*32 + c];
        sq = fmaf(e, S[2336 + c*16 + h], sq);
        sk = fmaf(e, S[2848 + c*16 + h], sk);
        sv = fmaf(e, S[3360 + c*16 + h], sv);
      }
      S[8032 + o2] = sq; S[8160 + o2] = sk; S[8288 + o2] = sv;
    }
  }
  __syncthreads();

  float* wsTab = ws + 16;
  for (int o = tid; o < 10074; o += 1024) {
    float r = 0.f; int dst;
    if (o < 4225) {                       // G1[a][b] = 0.25 * TQ[a].TK[b]
      const int a = o / 65, b = o % 65;
      #pragma unroll
      for (int h = 0; h < HD; ++h) r = fmaf(S[4912 + a*16 + h], S[5952 + b*16 + h], r);
      r *= 0.25f; dst = o;
    } else if (o < 4745) {                // G2[a][s]
      const int o2 = o - 4225, a = o2 >> 3, s2 = o2 & 7;
      #pragma unroll
      for (int h = 0; h < HD; ++h) r = fmaf(S[4912 + a*16 + h], S[8160 + s2*16 + h], r);
      r *= 0.25f; dst = 8450 + o2;
    } else if (o < 5265) {                // G3[t][b]
      const int o2 = o - 4745, t2 = o2 / 65, b = o2 % 65;
      #pragma unroll
      for (int h = 0; h < HD; ++h) r = fmaf(S[8032 + t2*16 + h], S[5952 + b*16 + h], r);
      r *= 0.25f; dst = 8970 + o2;
    } else if (o < 5329) {                // G4[t][s]
      const int o2 = o - 5265, t2 = o2 >> 3, s2 = o2 & 7;
      #pragma unroll
      for (int h = 0; h < HD; ++h) r = fmaf(S[8032 + t2*16 + h], S[8160 + s2*16 + h], r);
      r *= 0.25f; dst = 9490 + o2;
    } else if (o < 9554) {                // TVL[a][j]
      const int o2 = o - 5329, a = o2 / 65, j = o2 % 65;
      #pragma unroll
      for (int h = 0; h < HD; ++h) r = fmaf(S[6992 + a*16 + h], S[3872 + h*65 + j], r);
      dst = 4225 + o2;
    } else {                              // PVL[s][j]
      const int o2 = o - 9554, s2 = o2 / 65, j = o2 % 65;
      #pragma unroll
      for (int h = 0; h < HD; ++h) r = fmaf(S[8288 + s2*16 + h], S[3872 + h*65 + j], r);
      dst = o;
    }
    wsTab[dst] = r;
  }
}

// ---- main kernel: 1024 blocks x 512 threads; 1 wave handles 8 batches ----
__global__ __launch_bounds__(512, 6) void bigram_main(
    const int* __restrict__ idx, const int* __restrict__ tgt,
    const float* __restrict__ blm, const float* __restrict__ ws,
    float* __restrict__ wsacc, float* __restrict__ out)
{
  __shared__ __align__(16) float S[10074];
  __shared__ float red[8];
  const int tid = threadIdx.x;
  const float* wsTab = ws + 16;
  {
    const float4* t4 = (const float4*)wsTab;
    float4* s4 = (float4*)S;
    for (int o = tid; o < 2518; o += 512) s4[o] = t4[o];   // 10072 floats
    if (tid < 2) S[10072 + tid] = wsTab[10072 + tid];
  }
  const int lane = tid & 63;
  const int w    = tid >> 6;                 // 0..7
  const int t    = lane >> 3;
  const int s    = lane & 7;
  const float blmj  = blm[lane];
  const float blm64 = blm[64];
  const int gw = blockIdx.x * 8 + w;         // 8192 waves total
  const int iv = idx[gw*64 + lane];          // element (itb*8+p) lives at lane itb*8+p
  const int tv = tgt[gw*64 + lane];
  __syncthreads();

  const float g4 = S[9490 + lane];           // G4[t][s], lane == t*8+s
  float pvl[8], pvl64[8];
  #pragma unroll
  for (int k = 0; k < 8; ++k) {
    pvl[k]   = S[9554 + k*65 + lane];        // PVL[s=k][j=lane]
    pvl64[k] = S[9554 + k*65 + 64];
  }

  float acc_lsm = 0.f, acc_tl = 0.f;
  for (int itb = 0; itb < 8; ++itb) {
    const int base = itb * 8;
    const int av  = __shfl(iv, base + s);    // token at key position s
    const int a_t = __shfl(iv, base + t);    // token at query position t
    // scaled causal score, lane = (t,s)
    float wr = S[a_t*65 + av] + S[8450 + a_t*8 + s] + S[8970 + t*65 + av] + g4;
    float e = (t >= s) ? __expf(wr) : 0.f;   // softmax over t (per column s)
    float sm = e;
    sm += __shfl_xor(sm, 8); sm += __shfl_xor(sm, 16); sm += __shfl_xor(sm, 32);
    const float wsm = __fdividef(e, sm);     // wei[t][s] at lane t*8+s
    // M[k][j=lane] = TVL[a_k][j] + PVL[k][j]; col 64 uniform across lanes
    float Ms[8], Ms64[8];
    #pragma unroll
    for (int k = 0; k < 8; ++k) {
      const int ak = __builtin_amdgcn_readlane(iv, base + k);
      Ms[k]   = S[4225 + ak*65 + lane] + pvl[k];
      Ms64[k] = S[4225 + ak*65 + 64]  + pvl64[k];
    }
    const int rowbase = (gw*8 + itb) * 520;
    float ee[8];
    #pragma unroll
    for (int tt = 0; tt < 8; ++tt) {
      float lg = blmj, lg64 = blm64;
      #pragma unroll
      for (int k = 0; k < 8; ++k) {
        const float wk = readlane_f(wsm, tt*8 + k);   // wei[tt][k]
        lg   = fmaf(wk, Ms[k],   lg);
        lg64 = fmaf(wk, Ms64[k], lg64);
      }
      out[rowbase + tt*65 + lane] = lg;
      if (lane == 63) out[rowbase + tt*65 + 64] = lg64;
      float x = __expf(lg);
      if (lane == 63) x += __expf(lg64);     // fold col 64 into lane 63
      ee[tt] = x;
      const int tg  = __builtin_amdgcn_readlane(tv, base + tt);
      const int tgc = tg < 64 ? tg : 0;
      const float l_at_tg = readlane_f(lg, tgc);
      acc_tl += (tg < 64) ? l_at_tg : lg64;  // uniform across lanes
    }
    // row sums: reduce each ee[tt] within the 8-lane octet (xor 1,2,4),
    // select r = ee[u] (u = lane&7), then reduce across octets (xor 8,16,32).
    #pragma unroll
    for (int tt = 0; tt < 8; ++tt) {
      ee[tt] += __shfl_xor(ee[tt], 1);
      ee[tt] += __shfl_xor(ee[tt], 2);
      ee[tt] += __shfl_xor(ee[tt], 4);
    }
    const int u = lane & 7;
    float r01 = (u & 1) ? ee[1] : ee[0];
    float r23 = (u & 1) ? ee[3] : ee[2];
    float r45 = (u & 1) ? ee[5] : ee[4];
    float r67 = (u & 1) ? ee[7] : ee[6];
    float r03 = (u & 2) ? r23 : r01;
    float r47 = (u & 2) ? r67 : r45;
    float r   = (u & 4) ? r47 : r03;
    r += __shfl_xor(r, 8); r += __shfl_xor(r, 16); r += __shfl_xor(r, 32);
    acc_lsm += __logf(r);                    // row u, 8 lane-copies per row
  }
  float v = acc_lsm * 0.125f - acc_tl * 0.015625f;
  v += __shfl_xor(v, 1); v += __shfl_xor(v, 2);  v += __shfl_xor(v, 4);
  v += __shfl_xor(v, 8); v += __shfl_xor(v, 16); v += __shfl_xor(v, 32);
  if (lane == 0) red[w] = v;
  __syncthreads();
  if (tid == 0) {
    float acc = red[0] + red[1] + red[2] + red[3] + red[4] + red[5] + red[6] + red[7];
    atomicAdd(wsacc, acc);
  }
}

__global__ void bigram_fin(const float* __restrict__ ws, float* __restrict__ out) {
  if (threadIdx.x == 0) out[NLOG] = ws[0] * (1.0f / (float)NROWS);
}

extern "C" void kernel_launch(void* const* d_in, const int* in_sizes, int n_in,
                              void* d_out, int out_size, void* d_ws, size_t ws_size,
                              hipStream_t stream) {
  const int* idx = (const int*)d_in[0];
  const int* tgt = (const int*)d_in[1];
  float* ws = (float*)d_ws;
  float* out = (float*)d_out;

  bigram_tables<<<1, 1024, 0, stream>>>((const float*)d_in[2], (const float*)d_in[3],
                                        (const float*)d_in[4], (const float*)d_in[5],
                                        (const float*)d_in[6], (const float*)d_in[7],
                                        (const float*)d_in[8], (const float*)d_in[9],
                                        (const float*)d_in[10], ws);
  bigram_main<<<1024, 512, 0, stream>>>(idx, tgt, (const float*)d_in[11], ws, ws, out);
  bigram_fin<<<1, 1, 0, stream>>>(ws, out);
}